// Round 1
// baseline (852.647 us; speedup 1.0000x reference)
//
#include <hip/hip_runtime.h>
#include <hip/hip_bf16.h>

// Problem constants (B=2, S=2048, D=1024, E=8, H=4096)
#define NTOK 4096
#define DDIM 1024
#define HDIM 4096
#define NEXP 8
#define NPAIR (NTOK * 2)
#define BM 128
#define BK 64
#define MAXT 72  // max M-tiles: 8192/128 + 8 partials (bound)

typedef __attribute__((ext_vector_type(8))) short bf16x8;  // 8 bf16 = 4 VGPRs
typedef __attribute__((ext_vector_type(4))) float f32x4;

struct Misc {
  float enorm[NEXP];
  int cnt[NEXP];
  int cursor[NEXP];
  int nt;
  int pad;
  int te[MAXT];
  int tp0[MAXT];
  int tp1[MAXT];
  int gidx[NTOK * 2];
  float twt[NTOK * 2];
  int rows[NPAIR];
  float pwt[NPAIR];
};

// ws layout (bytes). Total required ~218.3 MB.
#define OFF_W1T 0ull
#define OFF_W2T 67108864ull
#define OFF_H 134217728ull
#define OFF_XG 201326592ull
#define OFF_MISC 218103808ull

__device__ __forceinline__ unsigned short f2bf(float f) {
  // RTNE fp32 -> bf16 (no NaN inputs here)
  unsigned int u = __float_as_uint(f);
  u += 0x7fffu + ((u >> 16) & 1u);
  return (unsigned short)(u >> 16);
}

// ---------- expert embedding norms ----------
__global__ __launch_bounds__(512) void enorm_k(const float* __restrict__ emb, Misc* mi) {
  int w = threadIdx.x >> 6, l = threadIdx.x & 63;
  const float* r = emb + (size_t)w * DDIM;
  float s = 0.f;
  for (int i = l; i < DDIM; i += 64) {
    float v = r[i];
    s += v * v;
  }
  #pragma unroll
  for (int o = 32; o; o >>= 1) s += __shfl_xor(s, o);
  if (l == 0) mi->enorm[w] = sqrtf(s);
}

// ---------- per-token routing: one wave per token ----------
__global__ __launch_bounds__(64) void route_k(const float* __restrict__ x,
                                              const float* __restrict__ emb,
                                              const float* __restrict__ cache, Misc* mi) {
  int n = blockIdx.x, l = threadIdx.x;
  const float* xr = x + (size_t)n * DDIM;
  float s[NEXP];
  #pragma unroll
  for (int e = 0; e < NEXP; e++) s[e] = 0.f;
  float nr = 0.f;
  for (int i = l; i < DDIM; i += 64) {
    float xv = xr[i];
    nr += xv * xv;
    #pragma unroll
    for (int e = 0; e < NEXP; e++) s[e] += xv * emb[e * DDIM + i];
  }
  #pragma unroll
  for (int o = 32; o; o >>= 1) {
    nr += __shfl_xor(nr, o);
    #pragma unroll
    for (int e = 0; e < NEXP; e++) s[e] += __shfl_xor(s[e], o);
  }
  if (l == 0) {
    float tn = sqrtf(nr) + 1e-8f;
    // top-7-of-8 by sim == exclude argmin(sim); ties -> keep highest index excluded
    int exc = 0;
    float mn = s[0];
    for (int e = 1; e < NEXP; e++)
      if (s[e] <= mn) {
        mn = s[e];
        exc = e;
      }
    float sc[NEXP];
    for (int e = 0; e < NEXP; e++)
      sc[e] = s[e] / (tn * (mi->enorm[e] + 1e-8f)) + 0.1f * cache[e];
    // top-2 by score over the local-7; lax.top_k tie order == larger sim first, then lower idx
    int g0 = -1, g1 = -1;
    for (int e = 0; e < NEXP; e++) {
      if (e == exc) continue;
      if (g0 < 0 || sc[e] > sc[g0] || (sc[e] == sc[g0] && s[e] > s[g0])) g0 = e;
    }
    for (int e = 0; e < NEXP; e++) {
      if (e == exc || e == g0) continue;
      if (g1 < 0 || sc[e] > sc[g1] || (sc[e] == sc[g1] && s[e] > s[g1])) g1 = e;
    }
    float e1 = expf(sc[g1] - sc[g0]);
    float w0 = 1.f / (1.f + e1);
    float w1 = e1 * w0;
    mi->gidx[2 * n] = g0;
    mi->gidx[2 * n + 1] = g1;
    mi->twt[2 * n] = w0;
    mi->twt[2 * n + 1] = w1;
    atomicAdd(mi->cnt + g0, 1);
    atomicAdd(mi->cnt + g1, 1);
  }
}

// ---------- scan counts -> offsets + tile table ----------
__global__ void scan_k(Misc* mi) {
  if (threadIdx.x != 0) return;
  int off = 0, t = 0;
  for (int e = 0; e < NEXP; e++) {
    mi->cursor[e] = off;
    int c = mi->cnt[e];
    for (int r = 0; r < c; r += BM) {
      mi->te[t] = e;
      mi->tp0[t] = off + r;
      int hi = (r + BM < c) ? (r + BM) : c;
      mi->tp1[t] = off + hi;
      t++;
    }
    off += c;
  }
  mi->nt = t;
}

// ---------- scatter tokens into expert-sorted pair lists ----------
__global__ __launch_bounds__(256) void scatter_k(Misc* mi) {
  int n = blockIdx.x * 256 + threadIdx.x;
  if (n >= NTOK) return;
  #pragma unroll
  for (int k = 0; k < 2; k++) {
    int e = mi->gidx[2 * n + k];
    int p = atomicAdd(mi->cursor + e, 1);
    mi->rows[p] = n;
    mi->pwt[p] = mi->twt[2 * n + k];
  }
}

// ---------- gather selected token rows fp32 -> bf16 ----------
__global__ __launch_bounds__(64) void gather_k(const float* __restrict__ x, const Misc* __restrict__ mi,
                                               unsigned short* __restrict__ xg) {
  int p = blockIdx.x, l = threadIdx.x;
  const float4* src = (const float4*)(x + (size_t)mi->rows[p] * DDIM);
  uint2* dst = (uint2*)(xg + (size_t)p * DDIM);
  #pragma unroll
  for (int j = 0; j < 4; j++) {
    float4 v = src[l + j * 64];
    uint2 o;
    o.x = (unsigned)f2bf(v.x) | ((unsigned)f2bf(v.y) << 16);
    o.y = (unsigned)f2bf(v.z) | ((unsigned)f2bf(v.w) << 16);
    dst[l + j * 64] = o;
  }
}

// ---------- transpose-convert weights: in [E][R][C] fp32 -> out [E][C][R] bf16 ----------
__global__ __launch_bounds__(256) void wconv_k(const float* __restrict__ in,
                                               unsigned short* __restrict__ out, int R, int C) {
  __shared__ float tile[64][65];
  int e = blockIdx.z;
  size_t base = (size_t)e * R * C;
  int c0 = blockIdx.x * 64, r0 = blockIdx.y * 64;
  int t = threadIdx.x;
  #pragma unroll
  for (int i = 0; i < 16; i++) {
    int idx = i * 256 + t;
    int r = idx >> 6, c = idx & 63;
    tile[r][c] = in[base + (size_t)(r0 + r) * C + (c0 + c)];
  }
  __syncthreads();
  #pragma unroll
  for (int i = 0; i < 16; i++) {
    int idx = i * 256 + t;
    int r = idx >> 6, c = idx & 63;
    out[base + (size_t)(c0 + r) * R + (r0 + c)] = f2bf(tile[c][r]);
  }
}

// ---------- MFMA GEMM: C[pairs x N] = A[pairs x K] * B_e^T, m97 structure ----------
// A: [NPAIR][K] bf16 row-major. B: [E][N][K] bf16 (B^T layout, k-contiguous rows).
// MODE 0: epilogue bias+gelu -> hout bf16. MODE 1: epilogue bias, *weight, atomicAdd -> out.
template <int MODE>
__global__ __launch_bounds__(256) void gemm_k(const unsigned short* __restrict__ A,
                                              const unsigned short* __restrict__ B,
                                              const float* __restrict__ bias,
                                              unsigned short* __restrict__ hout,
                                              float* __restrict__ out,
                                              const Misc* __restrict__ mi, int K, int N) {
  int tb = blockIdx.y;
  if (tb >= mi->nt) return;
  int e = mi->te[tb], p0 = mi->tp0[tb], p1 = mi->tp1[tb];
  int n0 = blockIdx.x * 128;
  __shared__ unsigned short Alds[BM * BK];
  __shared__ unsigned short Blds[BM * BK];
  int t = threadIdx.x, w = t >> 6, l = t & 63;
  int wr = w >> 1, wc = w & 1;
  f32x4 zero = {0.f, 0.f, 0.f, 0.f};
  f32x4 acc[4][4];
  #pragma unroll
  for (int m = 0; m < 4; m++)
    #pragma unroll
    for (int n = 0; n < 4; n++) acc[m][n] = zero;
  const unsigned short* Be = B + (size_t)e * N * K;
  int KT = K >> 6;
  int srow = l >> 3;          // row within 8-row chunk
  int scol = (l & 7) * 16;    // byte col within 128B row
  for (int kt = 0; kt < KT; ++kt) {
    int kb = kt * 128;  // byte offset along K
    #pragma unroll
    for (int j = 0; j < 4; j++) {
      int chunk = w * 4 + j;  // 16 chunks of 1KB cover the 16KB tile
      int arow = p0 + chunk * 8 + srow;
      if (arow >= NPAIR) arow = NPAIR - 1;  // clamp overhang (outputs discarded)
      const char* ga = (const char*)A + (size_t)arow * K * 2 + kb + scol;
      __builtin_amdgcn_global_load_lds((const __attribute__((address_space(1))) void*)ga,
                                       (__attribute__((address_space(3))) void*)((char*)Alds + chunk * 1024),
                                       16, 0, 0);
      int brow = n0 + chunk * 8 + srow;
      const char* gb = (const char*)Be + (size_t)brow * K * 2 + kb + scol;
      __builtin_amdgcn_global_load_lds((const __attribute__((address_space(1))) void*)gb,
                                       (__attribute__((address_space(3))) void*)((char*)Blds + chunk * 1024),
                                       16, 0, 0);
    }
    __syncthreads();  // drains vmcnt: LDS tiles ready
    #pragma unroll
    for (int kk = 0; kk < 2; kk++) {
      bf16x8 af[4], bfr[4];
      #pragma unroll
      for (int m = 0; m < 4; m++) {
        int row = wr * 64 + m * 16 + (l & 15);
        af[m] = *(const bf16x8*)((const char*)Alds + row * 128 + kk * 64 + (l >> 4) * 16);
      }
      #pragma unroll
      for (int n = 0; n < 4; n++) {
        int row = wc * 64 + n * 16 + (l & 15);
        bfr[n] = *(const bf16x8*)((const char*)Blds + row * 128 + kk * 64 + (l >> 4) * 16);
      }
      #pragma unroll
      for (int m = 0; m < 4; m++)
        #pragma unroll
        for (int n = 0; n < 4; n++)
          acc[m][n] = __builtin_amdgcn_mfma_f32_16x16x32_bf16(af[m], bfr[n], acc[m][n], 0, 0, 0);
    }
    __syncthreads();  // protect LDS before next stage
  }
  // epilogue: D layout col=lane&15, row=(lane>>4)*4+j
  int cbase = n0 + wc * 64 + (l & 15);
  int rbase = wr * 64 + (l >> 4) * 4;
  float bv[4];
  #pragma unroll
  for (int n = 0; n < 4; n++) bv[n] = bias[e * N + cbase + n * 16];
  #pragma unroll
  for (int m = 0; m < 4; m++) {
    #pragma unroll
    for (int j = 0; j < 4; j++) {
      int pr = p0 + rbase + m * 16 + j;
      if (pr >= p1) continue;
      if (MODE == 0) {
        #pragma unroll
        for (int n = 0; n < 4; n++) {
          float v = acc[m][n][j] + bv[n];
          float g = 0.5f * v * (1.f + erff(v * 0.70710678118654752f));
          hout[(size_t)pr * N + (cbase + n * 16)] = f2bf(g);
        }
      } else {
        float wgt = mi->pwt[pr];
        int tok = mi->rows[pr];
        #pragma unroll
        for (int n = 0; n < 4; n++) {
          float v = acc[m][n][j] + bv[n];
          atomicAdd(out + (size_t)tok * DDIM + (cbase + n * 16), wgt * v);
        }
      }
    }
  }
}

extern "C" void kernel_launch(void* const* d_in, const int* in_sizes, int n_in, void* d_out,
                              int out_size, void* d_ws, size_t ws_size, hipStream_t stream) {
  const float* x = (const float*)d_in[0];
  const float* emb = (const float*)d_in[1];
  const float* W1 = (const float*)d_in[2];
  const float* b1 = (const float*)d_in[3];
  const float* W2 = (const float*)d_in[4];
  const float* b2 = (const float*)d_in[5];
  const float* cache = (const float*)d_in[6];
  float* out = (float*)d_out;
  char* ws = (char*)d_ws;
  unsigned short* W1T = (unsigned short*)(ws + OFF_W1T);
  unsigned short* W2T = (unsigned short*)(ws + OFF_W2T);
  unsigned short* hb = (unsigned short*)(ws + OFF_H);
  unsigned short* xg = (unsigned short*)(ws + OFF_XG);
  Misc* mi = (Misc*)(ws + OFF_MISC);
  // requires ws_size >= ~218.3 MB

  hipMemsetAsync(out, 0, (size_t)NTOK * DDIM * sizeof(float), stream);
  hipMemsetAsync(mi, 0, sizeof(Misc), stream);

  enorm_k<<<1, 512, 0, stream>>>(emb, mi);
  route_k<<<NTOK, 64, 0, stream>>>(x, emb, cache, mi);
  scan_k<<<1, 1, 0, stream>>>(mi);
  scatter_k<<<NTOK / 256, 256, 0, stream>>>(mi);
  gather_k<<<NPAIR, 64, 0, stream>>>(x, mi, xg);
  // W1 [E][D][H] -> W1T [E][H][D]; W2 [E][H][D] -> W2T [E][D][H]
  wconv_k<<<dim3(HDIM / 64, DDIM / 64, NEXP), 256, 0, stream>>>(W1, W1T, DDIM, HDIM);
  wconv_k<<<dim3(DDIM / 64, HDIM / 64, NEXP), 256, 0, stream>>>(W2, W2T, HDIM, DDIM);
  // GEMM1: h = gelu(xg @ W1 + b1), K=D, N=H
  gemm_k<0><<<dim3(HDIM / 128, MAXT), 256, 0, stream>>>(xg, W1T, b1, hb, nullptr, mi, DDIM, HDIM);
  // GEMM2: out += w * (h @ W2 + b2), K=H, N=D
  gemm_k<1><<<dim3(DDIM / 128, MAXT), 256, 0, stream>>>(hb, W2T, b2, nullptr, out, mi, HDIM, DDIM);
}

// Round 2
// 747.041 us; speedup vs baseline: 1.1414x; 1.1414x over previous
//
#include <hip/hip_runtime.h>
#include <hip/hip_bf16.h>

// Problem constants (B=2, S=2048, D=1024, E=8, H=4096)
#define NTOK 4096
#define DDIM 1024
#define HDIM 4096
#define NEXP 8
#define NPAIR (NTOK * 2)
#define BMT 256   // GEMM M tile
#define MAXT 40   // max M-tiles: 8192/256 + 8 partials

typedef __attribute__((ext_vector_type(8))) short bf16x8;  // 8 bf16 = 4 VGPRs
typedef __attribute__((ext_vector_type(4))) float f32x4;

struct Misc {
  float enorm[NEXP];
  int cnt[NEXP];
  int cursor[NEXP];
  int nt;
  int pad;
  int te[MAXT];
  int tp0[MAXT];
  int tp1[MAXT];
  int gidx[NTOK * 2];
  float twt[NTOK * 2];
  int ppos[NTOK * 2];
  int rows[NPAIR];
  float pwt[NPAIR];
};

// ws layout (bytes), total ~209.3 MiB (<= round-1's 218 which fit):
// [W2T 64MiB][h 64MiB][xg 16MiB][W1T 64MiB][misc]
// outp (2 x 32MiB fp32 split-K slices) overlays xg+W1T (dead during GEMM2).
#define OFF_W2T 0ull
#define OFF_H 0x4000000ull
#define OFF_XG 0x8000000ull
#define OFF_W1T 0x9000000ull
#define OFF_OUTP 0x8000000ull
#define OFF_MISC 0xD000000ull

__device__ __forceinline__ unsigned short f2bf(float f) {
  unsigned int u = __float_as_uint(f);
  u += 0x7fffu + ((u >> 16) & 1u);
  return (unsigned short)(u >> 16);
}

// ---------- expert embedding norms ----------
__global__ __launch_bounds__(512) void enorm_k(const float* __restrict__ emb, Misc* mi) {
  int w = threadIdx.x >> 6, l = threadIdx.x & 63;
  const float* r = emb + (size_t)w * DDIM;
  float s = 0.f;
  for (int i = l; i < DDIM; i += 64) {
    float v = r[i];
    s += v * v;
  }
  #pragma unroll
  for (int o = 32; o; o >>= 1) s += __shfl_xor(s, o);
  if (l == 0) mi->enorm[w] = sqrtf(s);
}

// ---------- per-token routing: one wave per token ----------
__global__ __launch_bounds__(64) void route_k(const float* __restrict__ x,
                                              const float* __restrict__ emb,
                                              const float* __restrict__ cache, Misc* mi) {
  int n = blockIdx.x, l = threadIdx.x;
  const float* xr = x + (size_t)n * DDIM;
  float s[NEXP];
  #pragma unroll
  for (int e = 0; e < NEXP; e++) s[e] = 0.f;
  float nr = 0.f;
  for (int i = l; i < DDIM; i += 64) {
    float xv = xr[i];
    nr += xv * xv;
    #pragma unroll
    for (int e = 0; e < NEXP; e++) s[e] += xv * emb[e * DDIM + i];
  }
  #pragma unroll
  for (int o = 32; o; o >>= 1) {
    nr += __shfl_xor(nr, o);
    #pragma unroll
    for (int e = 0; e < NEXP; e++) s[e] += __shfl_xor(s[e], o);
  }
  if (l == 0) {
    float tn = sqrtf(nr) + 1e-8f;
    int exc = 0;
    float mn = s[0];
    for (int e = 1; e < NEXP; e++)
      if (s[e] <= mn) {
        mn = s[e];
        exc = e;
      }
    float sc[NEXP];
    for (int e = 0; e < NEXP; e++)
      sc[e] = s[e] / (tn * (mi->enorm[e] + 1e-8f)) + 0.1f * cache[e];
    int g0 = -1, g1 = -1;
    for (int e = 0; e < NEXP; e++) {
      if (e == exc) continue;
      if (g0 < 0 || sc[e] > sc[g0] || (sc[e] == sc[g0] && s[e] > s[g0])) g0 = e;
    }
    for (int e = 0; e < NEXP; e++) {
      if (e == exc || e == g0) continue;
      if (g1 < 0 || sc[e] > sc[g1] || (sc[e] == sc[g1] && s[e] > s[g1])) g1 = e;
    }
    float e1 = expf(sc[g1] - sc[g0]);
    float w0 = 1.f / (1.f + e1);
    float w1 = e1 * w0;
    mi->gidx[2 * n] = g0;
    mi->gidx[2 * n + 1] = g1;
    mi->twt[2 * n] = w0;
    mi->twt[2 * n + 1] = w1;
    atomicAdd(mi->cnt + g0, 1);
    atomicAdd(mi->cnt + g1, 1);
  }
}

// ---------- scan counts -> offsets + tile table (BM=256) ----------
__global__ void scan_k(Misc* mi) {
  if (threadIdx.x != 0) return;
  int off = 0, t = 0;
  for (int e = 0; e < NEXP; e++) {
    mi->cursor[e] = off;
    int c = mi->cnt[e];
    for (int r = 0; r < c; r += BMT) {
      mi->te[t] = e;
      mi->tp0[t] = off + r;
      int hi = (r + BMT < c) ? (r + BMT) : c;
      mi->tp1[t] = off + hi;
      t++;
    }
    off += c;
  }
  mi->nt = t;
}

// ---------- scatter tokens into expert-sorted pair lists ----------
__global__ __launch_bounds__(256) void scatter_k(Misc* mi) {
  int n = blockIdx.x * 256 + threadIdx.x;
  if (n >= NTOK) return;
  #pragma unroll
  for (int k = 0; k < 2; k++) {
    int e = mi->gidx[2 * n + k];
    int p = atomicAdd(mi->cursor + e, 1);
    mi->rows[p] = n;
    mi->pwt[p] = mi->twt[2 * n + k];
    mi->ppos[2 * n + k] = p;
  }
}

// ---------- gather selected token rows fp32 -> bf16 ----------
__global__ __launch_bounds__(64) void gather_k(const float* __restrict__ x, const Misc* __restrict__ mi,
                                               unsigned short* __restrict__ xg) {
  int p = blockIdx.x, l = threadIdx.x;
  const float4* src = (const float4*)(x + (size_t)mi->rows[p] * DDIM);
  uint2* dst = (uint2*)(xg + (size_t)p * DDIM);
  #pragma unroll
  for (int j = 0; j < 4; j++) {
    float4 v = src[l + j * 64];
    uint2 o;
    o.x = (unsigned)f2bf(v.x) | ((unsigned)f2bf(v.y) << 16);
    o.y = (unsigned)f2bf(v.z) | ((unsigned)f2bf(v.w) << 16);
    dst[l + j * 64] = o;
  }
}

// ---------- transpose-convert weights: in [E][R][C] fp32 -> out [E][C][R] bf16 ----------
__global__ __launch_bounds__(256) void wconv_k(const float* __restrict__ in,
                                               unsigned short* __restrict__ out, int R, int C) {
  __shared__ float tile[64][65];
  int e = blockIdx.z;
  size_t base = (size_t)e * R * C;
  int c0 = blockIdx.x * 64, r0 = blockIdx.y * 64;
  int t = threadIdx.x;
  #pragma unroll
  for (int i = 0; i < 16; i++) {
    int idx = i * 256 + t;
    int r = idx >> 6, c = idx & 63;
    tile[r][c] = in[base + (size_t)(r0 + r) * C + (c0 + c)];
  }
  __syncthreads();
  #pragma unroll
  for (int i = 0; i < 16; i++) {
    int idx = i * 256 + t;
    int r = idx >> 6, c = idx & 63;
    out[base + (size_t)(c0 + r) * R + (r0 + c)] = f2bf(tile[c][r]);
  }
}

// ================= 256x256 8-wave phase-split MFMA GEMM =================
// A: [NPAIR][K] bf16 row-major. B: [E][N][K] bf16 (B^T layout).
// LDS: 2 buffers x (A[256][64] + B[256][64]) bf16, XOR-swizzled (T2, both sides):
//   phys_col_byte = logical ^ ((row&7)<<4); global_load_lds dest linear, source pre-swizzled.
// Schedule per K-tile: 4 phases x 16 MFMA; 2 gloads/phase; counted vmcnt(2) once per tile.
// MODE 0: bias+gelu -> hout bf16.  MODE 1: raw fp32 -> outp slice (split-K, no atomics).
#define GL(src, off)                                                                        \
  __builtin_amdgcn_global_load_lds((const __attribute__((address_space(1))) void*)(src),    \
                                   (__attribute__((address_space(3))) void*)(LDS + (off)),  \
                                   16, 0, 0)

template <int MODE>
__global__ __launch_bounds__(512, 2) void gemm8_k(const unsigned short* __restrict__ A,
                                                  const unsigned short* __restrict__ B,
                                                  const float* __restrict__ bias,
                                                  unsigned short* __restrict__ hout,
                                                  float* __restrict__ outp,
                                                  const Misc* __restrict__ mi, int K, int N,
                                                  int nk) {
  __shared__ char LDS[131072];
  // T1: bijective XCD swizzle over linearized grid (m204)
  int nwg = gridDim.x * gridDim.y * gridDim.z;
  int lin = (blockIdx.z * gridDim.y + blockIdx.y) * gridDim.x + blockIdx.x;
  int q = nwg >> 3, r = nwg & 7, xc = lin & 7;
  int wk = (xc < r ? xc * (q + 1) : r * (q + 1) + (xc - r) * q) + (lin >> 3);
  int nb = wk % gridDim.x;
  int rest = wk / gridDim.x;
  int tb = rest % gridDim.y;
  int ks = rest / gridDim.y;
  if (tb >= mi->nt) return;
  int e = mi->te[tb], p0 = mi->tp0[tb], p1 = mi->tp1[tb];
  int n0 = nb * 256;
  int k0 = ks * nk;
  int tid = threadIdx.x, w = tid >> 6, l = tid & 63;
  int wr = w >> 2, wc = w & 3;
  int srow = l >> 3;
  int scol = ((l & 7) ^ srow) << 4;  // pre-swizzled global source byte col
  size_t ldb = (size_t)K * 2;
  const char* Asrc[4];
  const char* Bsrc[4];
  #pragma unroll
  for (int j = 0; j < 4; j++) {
    int ar = p0 + j * 64 + w * 8 + srow;
    if (ar > NPAIR - 1) ar = NPAIR - 1;  // clamp overhang (rows discarded in epilogue)
    Asrc[j] = (const char*)A + (size_t)ar * ldb + scol;
    int br = n0 + j * 64 + w * 8 + srow;
    Bsrc[j] = (const char*)B + (size_t)e * N * ldb + (size_t)br * ldb + scol;
  }
  f32x4 acc[8][4];
  f32x4 zero = {0.f, 0.f, 0.f, 0.f};
  #pragma unroll
  for (int m = 0; m < 8; m++)
    #pragma unroll
    for (int n = 0; n < 4; n++) acc[m][n] = zero;
  int q4 = l >> 4, s3 = l & 7;
  int colk0 = ((q4 ^ (s3 & 3)) << 4) | ((s3 >> 2) << 6);  // swizzled read col (kk=0)
  int aoffB = (wr * 128 + (l & 15)) * 128 + colk0;
  int boffB = 32768 + (wc * 64 + (l & 15)) * 128 + colk0;

  // prologue: stage L(0) fully, then A0,A1 of L(1)  (matches steady-state vmcnt(2))
  long kb0 = (long)k0 * 128;
  #pragma unroll
  for (int j = 0; j < 4; j++) GL(Asrc[j] + kb0, j * 8192 + w * 1024);
  #pragma unroll
  for (int j = 0; j < 4; j++) GL(Bsrc[j] + kb0, 32768 + j * 8192 + w * 1024);
  if (nk > 1) {
    GL(Asrc[0] + kb0 + 128, 65536 + w * 1024);
    GL(Asrc[1] + kb0 + 128, 65536 + 8192 + w * 1024);
  }

  bf16x8 af[4][2], bf[4][2];
  for (int t = 0; t < nk; ++t) {
    int cb = (t & 1) << 16, nbuf = ((t + 1) & 1) << 16;
    long kb1 = (long)(k0 + t + 1) * 128;
    long kb2 = kb1 + 128;
    int ao = cb + aoffB, bo = cb + boffB;
    bool ld1 = (t + 1 < nk), ld2 = (t + 2 < nk);
    // ---- PH1: wait tile t landed; prefetch A2A3(t+1); read af_mh0 + bf_nh0; Q(0,0)
    if (ld1)
      asm volatile("s_waitcnt vmcnt(2)" ::: "memory");
    else
      asm volatile("s_waitcnt vmcnt(0)" ::: "memory");
    __builtin_amdgcn_s_barrier();
    asm volatile("" ::: "memory");
    if (ld1) {
      GL(Asrc[2] + kb1, nbuf + 2 * 8192 + w * 1024);
      GL(Asrc[3] + kb1, nbuf + 3 * 8192 + w * 1024);
    }
    #pragma unroll
    for (int m = 0; m < 4; m++)
      #pragma unroll
      for (int kk = 0; kk < 2; kk++)
        af[m][kk] = *(const bf16x8*)(LDS + ((ao + m * 2048) ^ (kk << 6)));
    #pragma unroll
    for (int n = 0; n < 2; n++)
      #pragma unroll
      for (int kk = 0; kk < 2; kk++)
        bf[n][kk] = *(const bf16x8*)(LDS + ((bo + n * 2048) ^ (kk << 6)));
    asm volatile("s_waitcnt lgkmcnt(0)" ::: "memory");
    __builtin_amdgcn_sched_barrier(0);
    __builtin_amdgcn_s_setprio(1);
    #pragma unroll
    for (int m = 0; m < 4; m++)
      #pragma unroll
      for (int n = 0; n < 2; n++)
        #pragma unroll
        for (int kk = 0; kk < 2; kk++)
          acc[m][n] = __builtin_amdgcn_mfma_f32_16x16x32_bf16(af[m][kk], bf[n][kk], acc[m][n], 0, 0, 0);
    __builtin_amdgcn_s_setprio(0);
    __builtin_amdgcn_s_barrier();
    asm volatile("" ::: "memory");
    // ---- PH2: prefetch B0B1(t+1); read bf_nh1; Q(0,1)
    if (ld1) {
      GL(Bsrc[0] + kb1, nbuf + 32768 + w * 1024);
      GL(Bsrc[1] + kb1, nbuf + 32768 + 8192 + w * 1024);
    }
    #pragma unroll
    for (int n = 0; n < 2; n++)
      #pragma unroll
      for (int kk = 0; kk < 2; kk++)
        bf[2 + n][kk] = *(const bf16x8*)(LDS + ((bo + (2 + n) * 2048) ^ (kk << 6)));
    asm volatile("s_waitcnt lgkmcnt(0)" ::: "memory");
    __builtin_amdgcn_sched_barrier(0);
    __builtin_amdgcn_s_setprio(1);
    #pragma unroll
    for (int m = 0; m < 4; m++)
      #pragma unroll
      for (int n = 0; n < 2; n++)
        #pragma unroll
        for (int kk = 0; kk < 2; kk++)
          acc[m][2 + n] = __builtin_amdgcn_mfma_f32_16x16x32_bf16(af[m][kk], bf[2 + n][kk], acc[m][2 + n], 0, 0, 0);
    __builtin_amdgcn_s_setprio(0);
    __builtin_amdgcn_s_barrier();
    asm volatile("" ::: "memory");
    // ---- PH3: prefetch B2B3(t+1); read af_mh1 (buf t fully consumed after this); Q(1,1)
    if (ld1) {
      GL(Bsrc[2] + kb1, nbuf + 32768 + 2 * 8192 + w * 1024);
      GL(Bsrc[3] + kb1, nbuf + 32768 + 3 * 8192 + w * 1024);
    }
    #pragma unroll
    for (int m = 0; m < 4; m++)
      #pragma unroll
      for (int kk = 0; kk < 2; kk++)
        af[m][kk] = *(const bf16x8*)(LDS + ((ao + 8192 + m * 2048) ^ (kk << 6)));
    asm volatile("s_waitcnt lgkmcnt(0)" ::: "memory");
    __builtin_amdgcn_sched_barrier(0);
    __builtin_amdgcn_s_setprio(1);
    #pragma unroll
    for (int m = 0; m < 4; m++)
      #pragma unroll
      for (int n = 0; n < 2; n++)
        #pragma unroll
        for (int kk = 0; kk < 2; kk++)
          acc[4 + m][2 + n] = __builtin_amdgcn_mfma_f32_16x16x32_bf16(af[m][kk], bf[2 + n][kk], acc[4 + m][2 + n], 0, 0, 0);
    __builtin_amdgcn_s_setprio(0);
    __builtin_amdgcn_s_barrier();
    asm volatile("" ::: "memory");
    // ---- PH4: prefetch A0A1(t+2) into current buf (safe: consumed at PH3); Q(1,0)
    if (ld2) {
      GL(Asrc[0] + kb2, cb + w * 1024);
      GL(Asrc[1] + kb2, cb + 8192 + w * 1024);
    }
    __builtin_amdgcn_s_setprio(1);
    #pragma unroll
    for (int m = 0; m < 4; m++)
      #pragma unroll
      for (int n = 0; n < 2; n++)
        #pragma unroll
        for (int kk = 0; kk < 2; kk++)
          acc[4 + m][n] = __builtin_amdgcn_mfma_f32_16x16x32_bf16(af[m][kk], bf[n][kk], acc[4 + m][n], 0, 0, 0);
    __builtin_amdgcn_s_setprio(0);
    __builtin_amdgcn_s_barrier();
    asm volatile("" ::: "memory");
  }
  // epilogue: D layout col=lane&15 (B side), row=(lane>>4)*4+jj (A side) — verified round 1
  int cbase = n0 + wc * 64 + (l & 15);
  if (MODE == 0) {
    float bv[4];
    #pragma unroll
    for (int n = 0; n < 4; n++) bv[n] = bias[e * N + cbase + n * 16];
    #pragma unroll
    for (int m = 0; m < 8; m++) {
      #pragma unroll
      for (int jj = 0; jj < 4; jj++) {
        int pr = p0 + wr * 128 + m * 16 + q4 * 4 + jj;
        if (pr >= p1) continue;
        #pragma unroll
        for (int n = 0; n < 4; n++) {
          float v = acc[m][n][jj] + bv[n];
          float g = 0.5f * v * (1.f + erff(v * 0.70710678118654752f));
          hout[(size_t)pr * N + cbase + n * 16] = f2bf(g);
        }
      }
    }
  } else {
    float* op = outp + (size_t)ks * NPAIR * DDIM;
    #pragma unroll
    for (int m = 0; m < 8; m++) {
      #pragma unroll
      for (int jj = 0; jj < 4; jj++) {
        int pr = p0 + wr * 128 + m * 16 + q4 * 4 + jj;
        if (pr >= p1) continue;
        #pragma unroll
        for (int n = 0; n < 4; n++) op[(size_t)pr * N + cbase + n * 16] = acc[m][n][jj];
      }
    }
  }
}

// ---------- combine: out[tok] = sum_k w_k * (slice0[p_k] + slice1[p_k] + b2[e_k]) ----------
__global__ __launch_bounds__(256) void combine_k(const float* __restrict__ op,
                                                 const float* __restrict__ b2,
                                                 const Misc* __restrict__ mi,
                                                 float* __restrict__ out) {
  int tok = blockIdx.x, i = threadIdx.x;
  int pa = mi->ppos[2 * tok], pb = mi->ppos[2 * tok + 1];
  float w0 = mi->twt[2 * tok], w1 = mi->twt[2 * tok + 1];
  int e0 = mi->gidx[2 * tok], e1 = mi->gidx[2 * tok + 1];
  const float4* o0 = (const float4*)op;
  const float4* o1 = (const float4*)(op + (size_t)NPAIR * DDIM);
  float4 r0a = o0[(size_t)pa * 256 + i], r1a = o1[(size_t)pa * 256 + i];
  float4 r0b = o0[(size_t)pb * 256 + i], r1b = o1[(size_t)pb * 256 + i];
  float4 va = ((const float4*)(b2 + (size_t)e0 * DDIM))[i];
  float4 vb = ((const float4*)(b2 + (size_t)e1 * DDIM))[i];
  float4 res;
  res.x = w0 * (r0a.x + r1a.x + va.x) + w1 * (r0b.x + r1b.x + vb.x);
  res.y = w0 * (r0a.y + r1a.y + va.y) + w1 * (r0b.y + r1b.y + vb.y);
  res.z = w0 * (r0a.z + r1a.z + va.z) + w1 * (r0b.z + r1b.z + vb.z);
  res.w = w0 * (r0a.w + r1a.w + va.w) + w1 * (r0b.w + r1b.w + vb.w);
  ((float4*)out)[(size_t)tok * 256 + i] = res;
}

extern "C" void kernel_launch(void* const* d_in, const int* in_sizes, int n_in, void* d_out,
                              int out_size, void* d_ws, size_t ws_size, hipStream_t stream) {
  const float* x = (const float*)d_in[0];
  const float* emb = (const float*)d_in[1];
  const float* W1 = (const float*)d_in[2];
  const float* b1 = (const float*)d_in[3];
  const float* W2 = (const float*)d_in[4];
  const float* b2 = (const float*)d_in[5];
  const float* cache = (const float*)d_in[6];
  float* out = (float*)d_out;
  char* ws = (char*)d_ws;
  unsigned short* W1T = (unsigned short*)(ws + OFF_W1T);
  unsigned short* W2T = (unsigned short*)(ws + OFF_W2T);
  unsigned short* hb = (unsigned short*)(ws + OFF_H);
  unsigned short* xg = (unsigned short*)(ws + OFF_XG);
  float* outp = (float*)(ws + OFF_OUTP);
  Misc* mi = (Misc*)(ws + OFF_MISC);

  hipMemsetAsync(mi, 0, sizeof(Misc), stream);

  enorm_k<<<1, 512, 0, stream>>>(emb, mi);
  route_k<<<NTOK, 64, 0, stream>>>(x, emb, cache, mi);
  scan_k<<<1, 1, 0, stream>>>(mi);
  scatter_k<<<NTOK / 256, 256, 0, stream>>>(mi);
  gather_k<<<NPAIR, 64, 0, stream>>>(x, mi, xg);
  // W1 [E][D][H] -> W1T [E][H][D]; W2 [E][H][D] -> W2T [E][D][H]
  wconv_k<<<dim3(HDIM / 64, DDIM / 64, NEXP), 256, 0, stream>>>(W1, W1T, DDIM, HDIM);
  wconv_k<<<dim3(DDIM / 64, HDIM / 64, NEXP), 256, 0, stream>>>(W2, W2T, HDIM, DDIM);
  // GEMM1: h = gelu(xg @ W1 + b1), K=D=1024 (16 K-tiles), N=H
  gemm8_k<0><<<dim3(HDIM / 256, MAXT, 1), 512, 0, stream>>>(xg, W1T, b1, hb, nullptr, mi, DDIM, HDIM, 16);
  // GEMM2: split-K=2 slices of raw (h @ W2), K=H=4096 (32 K-tiles each), N=D
  gemm8_k<1><<<dim3(DDIM / 256, MAXT, 2), 512, 0, stream>>>(hb, W2T, nullptr, nullptr, outp, mi, HDIM, DDIM, 32);
  // combine slices + bias + routing weights -> out
  combine_k<<<NTOK, 256, 0, stream>>>(outp, b2, mi, out);
}